// Round 8
// baseline (142.861 us; speedup 1.0000x reference)
//
#include <hip/hip_runtime.h>
#include <stdint.h>
#include <stddef.h>

// Problem constants (fixed by the reference):
//   x:[B=65536][D=128] f32, E:[C=64][L=64][D=128] f32, counts:[64][64] f32
//   out0 = max_l cos(x_b, E_{c,l})  [B][C]
//   out1 = counts + bincount of argmax_l  [C][L]
#define D      128
#define NCATS  64
#define NLEAF  64
#define NC_BLK 4     // categories per block (c-split x16): ALL tiles LDS-resident
#define BM     512   // rows per block (8 waves x 64 batch cols)
#define BIAS   32.0f // dot ~ N(0,1) -> biased value positive -> uint order == float order

// Workspace layout: e16 [0,1MB) | x16 [1MB,17MB) | xinv [17MB,17.25MB)
#define WS_E16_BYTES   (1u << 20)
#define WS_X16_BYTES   (16u << 20)
#define WS_XINV_BYTES  (65536u * 4u)
#define WS_NEEDED      ((size_t)WS_E16_BYTES + WS_X16_BYTES + WS_XINV_BYTES)

typedef _Float16 half8_t  __attribute__((ext_vector_type(8)));
typedef _Float16 half4h_t __attribute__((ext_vector_type(4)));
typedef float    float4_t __attribute__((ext_vector_type(4)));

__device__ __forceinline__ void async_ld16(const void* g, void* l) {
  __builtin_amdgcn_global_load_lds((const __attribute__((address_space(1))) uint32_t*)g,
                                   (__attribute__((address_space(3))) uint32_t*)l,
                                   16, 0, 0);
}

__device__ __forceinline__ unsigned umax2(unsigned a, unsigned b) { return a > b ? a : b; }
// Nested so the compiler fuses to v_max3_u32.
__device__ __forceinline__ unsigned umax3(unsigned a, unsigned b, unsigned c) {
  return umax2(umax2(a, b), c);
}

// ---------------------------------------------------------------------------
// Prep:
//  blocks [0,256): E rows -> unit-normalized fp16 in FRAGMENT-MAJOR order
//    (R15): per cat tile (16KB): frag (rt,s) at (rt*4+s)*1024, lane l's 16B
//    at l*16 with l = (cc&3)*16 + (row&15)  [= (q,wl)], bytes = E row
//    rt*16+wl, k-halfs (q+4s)*8..+8. Main's LDS read is then base+lane*16:
//    linear, ZERO bank conflicts (R14 counter: 4.66M conflict cycles ~ 4.4
//    per E-read), no addr math. Staging DMA is a linear copy either way.
//    Also seeds counts_out from cin (d_out is poisoned).
//  blocks [256,4352) (XP mode): x rows -> RAW fp16 in 16-row tiles
//    (addr = g*4096 + chunk*256 + (row&15)*16) + inv_x[row] (f32).
// ---------------------------------------------------------------------------
__global__ __launch_bounds__(256) void prep_kernel(const float* __restrict__ e,
                                                   const float* __restrict__ xf,
                                                   char* __restrict__ e16,
                                                   char* __restrict__ x16,
                                                   float* __restrict__ xinv,
                                                   const float* __restrict__ cin,
                                                   float* __restrict__ counts_out) {
  const int t  = threadIdx.x;
  const int rl = t >> 4;  // row within this block's 16
  const int cc = t & 15;  // 16B chunk (8 halfs) within row

  if (blockIdx.x < 256) {
    const int row = blockIdx.x * 16 + rl;
    const float* src = e + (size_t)row * D + cc * 8;
    float4_t v0 = *(const float4_t*)src;
    float4_t v1 = *(const float4_t*)(src + 4);
    float ss = v0.x*v0.x + v0.y*v0.y + v0.z*v0.z + v0.w*v0.w +
               v1.x*v1.x + v1.y*v1.y + v1.z*v1.z + v1.w*v1.w;
    ss += __shfl_xor(ss, 1);
    ss += __shfl_xor(ss, 2);
    ss += __shfl_xor(ss, 4);
    ss += __shfl_xor(ss, 8);
    const float inv = 1.0f / fmaxf(sqrtf(ss), 1e-8f);
    half8_t h;
    h[0] = (_Float16)(v0.x * inv); h[1] = (_Float16)(v0.y * inv);
    h[2] = (_Float16)(v0.z * inv); h[3] = (_Float16)(v0.w * inv);
    h[4] = (_Float16)(v1.x * inv); h[5] = (_Float16)(v1.y * inv);
    h[6] = (_Float16)(v1.z * inv); h[7] = (_Float16)(v1.w * inv);
    // Fragment-major dest: cat | frag (rt,s) | lane (q,wl).
    const int cat = row >> 6;
    const int rt  = (row >> 4) & 3;
    const int wl  = row & 15;
    const int s   = cc >> 2;   // k-group
    const int q   = cc & 3;    // quad
    char* dst = e16 + (size_t)cat * 16384 + (rt * 4 + s) * 1024 + (q * 16 + wl) * 16;
    *(half8_t*)dst = h;
    if (blockIdx.x < (NCATS * NLEAF) / 256)
      counts_out[blockIdx.x * 256 + t] = cin[blockIdx.x * 256 + t];
  } else {
    const int g   = blockIdx.x - 256;     // 16-row group 0..4095
    const int row = g * 16 + rl;          // 0..65535
    const float* src = xf + (size_t)row * D + cc * 8;
    float4_t v0 = *(const float4_t*)src;
    float4_t v1 = *(const float4_t*)(src + 4);
    float ss = v0.x*v0.x + v0.y*v0.y + v0.z*v0.z + v0.w*v0.w +
               v1.x*v1.x + v1.y*v1.y + v1.z*v1.z + v1.w*v1.w;
    ss += __shfl_xor(ss, 1);
    ss += __shfl_xor(ss, 2);
    ss += __shfl_xor(ss, 4);
    ss += __shfl_xor(ss, 8);
    const float inv = 1.0f / fmaxf(sqrtf(ss), 1e-8f);
    half8_t h;  // RAW fp16 (main multiplies inv at epilogue, as before)
    h[0] = (_Float16)v0.x; h[1] = (_Float16)v0.y;
    h[2] = (_Float16)v0.z; h[3] = (_Float16)v0.w;
    h[4] = (_Float16)v1.x; h[5] = (_Float16)v1.y;
    h[6] = (_Float16)v1.z; h[7] = (_Float16)v1.w;
    *(half8_t*)(x16 + (size_t)g * 4096 + cc * 256 + rl * 16) = h;
    if (cc == 0) xinv[row] = inv;
  }
}

// ---------------------------------------------------------------------------
// Main (R15): R14 chassis (NC_BLK=4 all-LDS-resident, ONE barrier, barrier-
// free ci loop, fp16 x16/xinv prep, max3 pack, 64-lane writers) + two
// counter-driven changes:
//  * Fragment-major ebuf: E ds_read = base + (rt*4+s)*1024 + lane*16 ->
//    linear pattern, zero bank conflicts (was ~4-way on every read,
//    4.66M conflict cycles), rowbase[]/xoff[] address math gone.
//  * __launch_bounds__(512,2): LDS (70.6KB) caps at 2 blocks/CU regardless,
//    so VGPR cap 128 is free headroom -> compiler can keep accs/pack in
//    VGPRs without AGPR shuffling. (R11/R12's cliffs were at 3-block LDS
//    shapes; here occupancy cap is LDS-fixed.)
// ---------------------------------------------------------------------------
template <bool XP>
__global__ __launch_bounds__(512, 2) void main_kernel(const float* __restrict__ x,
                                                      const char* __restrict__ e16,
                                                      const char* __restrict__ x16,
                                                      const float* __restrict__ xinv,
                                                      float* __restrict__ cos_out,
                                                      float* __restrict__ counts_out) {
  __shared__ __align__(16) char ebuf[NC_BLK][16384];     // 64 KB, fragment-major
  __shared__ unsigned hist[NC_BLK * NLEAF];              // 1 KB
  __shared__ __align__(16) _Float16 stage[BM * NC_BLK];  // 4 KB, 8 B/row

  const int tid  = threadIdx.x;
  const int w    = tid >> 6;    // wave 0..7
  const int lane = tid & 63;
  const int q    = lane >> 4;   // MFMA quad
  const int wl   = lane & 15;

  // XCD-aware decode: bid = c_idx*128 + rb_local*8 + xcd.
  const int xcd    = blockIdx.x & 7;
  const int rb     = xcd * 16 + ((blockIdx.x >> 3) & 15);
  const int c_base = (blockIdx.x >> 7) * NC_BLK;
  const int b_base = rb * BM;

  // Stage ALL 4 tiles now: wave w -> tile w>>1, half w&1 (8KB each, 8 loads).
  {
    const char* g = e16 + (size_t)(c_base + (w >> 1)) * 16384 + (w & 1) * 8192 + lane * 16;
    char* l = &ebuf[w >> 1][(w & 1) * 8192 + lane * 16];
#pragma unroll
    for (int j = 0; j < 8; ++j) async_ld16(g + j * 1024, l + j * 1024);
  }

  if (tid < NC_BLK * NLEAF) hist[tid] = 0;

  // B = x fragments (verified lane layout: B[n=lane&15][k=quad*8+j]):
  // tile nt covers batch rows b_base + w*64 + nt*16 + [0,16).
  half8_t bfrag[4][4];
  float inv_x[4];
  if constexpr (XP) {
    const size_t gbase = ((size_t)b_base >> 4) + (size_t)w * 4;
#pragma unroll
    for (int nt = 0; nt < 4; ++nt) {
      const char* xr = x16 + (gbase + nt) * 4096 + q * 256 + wl * 16;
#pragma unroll
      for (int s = 0; s < 4; ++s)
        bfrag[nt][s] = *(const half8_t*)(xr + s * 1024);  // 1KB/instr coalesced
      inv_x[nt] = xinv[b_base + w * 64 + nt * 16 + wl];
    }
  } else {
#pragma unroll
    for (int nt = 0; nt < 4; ++nt) {
      const int row = b_base + w * 64 + nt * 16 + wl;
      const float* xr = x + (size_t)row * D;
      float ss = 0.f;
#pragma unroll
      for (int s = 0; s < 4; ++s) {
        const float* p = xr + s * 32 + q * 8;
        float4_t v0 = *(const float4_t*)p;
        float4_t v1 = *(const float4_t*)(p + 4);
        half8_t h;
        h[0] = (_Float16)v0.x; h[1] = (_Float16)v0.y;
        h[2] = (_Float16)v0.z; h[3] = (_Float16)v0.w;
        h[4] = (_Float16)v1.x; h[5] = (_Float16)v1.y;
        h[6] = (_Float16)v1.z; h[7] = (_Float16)v1.w;
        bfrag[nt][s] = h;
        ss += v0.x*v0.x + v0.y*v0.y + v0.z*v0.z + v0.w*v0.w +
              v1.x*v1.x + v1.y*v1.y + v1.z*v1.z + v1.w*v1.w;
      }
      ss += __shfl_xor(ss, 16);
      ss += __shfl_xor(ss, 32);
      inv_x[nt] = 1.0f / fmaxf(sqrtf(ss), 1e-8f);
    }
  }

  const int lofs = lane * 16;               // fragment-major lane offset
  const unsigned idq = (unsigned)(q << 2);  // leaf-index bits {2,3} (lane const)
  const float4_t bias4 = {BIAS, BIAS, BIAS, BIAS};

  __syncthreads();  // ONE barrier: drains tile DMA (vmcnt0) + hist init

  // ----- barrier-free, wait-free ci loop -----
#pragma unroll
  for (int ci = 0; ci < NC_BLK; ++ci) {
    const char* cur = &ebuf[ci][lofs];

    // rt-outer: acc[4] (one per batch tile nt) live at a time. C/D layout:
    // col = lane&15 = batch-within-tile, row = q*4+reg = leaf-within-tile.
    // Keys carry leaf idx bits {0,1}=reg, {4,5}=rt at pack time; bits {2,3}
    // (=q) are zero in-lane and OR'd once before the cross-lane combine.
    unsigned pk[4];
    __builtin_amdgcn_s_setprio(1);
#pragma unroll
    for (int rt = 0; rt < 4; ++rt) {
      float4_t acc[4];
#pragma unroll
      for (int s = 0; s < 4; ++s) {
        half8_t ef = *(const half8_t*)(cur + (rt * 4 + s) * 1024);  // linear, conflict-free
#pragma unroll
        for (int nt = 0; nt < 4; ++nt)
          acc[nt] = __builtin_amdgcn_mfma_f32_16x16x32_f16(
              ef, bfrag[nt][s], (s == 0) ? bias4 : acc[nt], 0, 0, 0);
      }
      // Pack via max3 tree (keys are positive floats: dot+BIAS ~ 32+-5).
#pragma unroll
      for (int nt = 0; nt < 4; ++nt) {
        const unsigned k0 = (__float_as_uint(acc[nt][0]) & 0xFFFFFFC0u) | (unsigned)(rt * 16 + 0);
        const unsigned k1 = (__float_as_uint(acc[nt][1]) & 0xFFFFFFC0u) | (unsigned)(rt * 16 + 1);
        const unsigned k2 = (__float_as_uint(acc[nt][2]) & 0xFFFFFFC0u) | (unsigned)(rt * 16 + 2);
        const unsigned k3 = (__float_as_uint(acc[nt][3]) & 0xFFFFFFC0u) | (unsigned)(rt * 16 + 3);
        const unsigned m  = umax3(k0, k1, k2);
        pk[nt] = (rt == 0) ? umax2(m, k3) : umax3(m, k3, pk[nt]);
      }
    }
    __builtin_amdgcn_s_setprio(0);

    // Cross-lane: combine the 4 quads of this batch col. EXPLICIT TEMPS,
    // unconditional shuffles (R3 lesson: never a cross-lane op in a ternary).
#pragma unroll
    for (int nt = 0; nt < 4; ++nt) {
      unsigned v = pk[nt] | idq;
      unsigned t = (unsigned)__shfl_xor((int)v, 16);
      v = (v > t) ? v : t;
      t = (unsigned)__shfl_xor((int)v, 32);
      v = (v > t) ? v : t;
      pk[nt] = v;  // quad-uniform for this wl
    }

    // Writers spread over all 64 lanes: lane (q,wl) handles nt=q. pk[q] is
    // quad-uniform; inv_x[nt] is wl-determined (q-independent) -> every lane
    // holds the right inv. Constant-index selects only (no runtime indexing).
    {
      const unsigned pk01 = (q == 0) ? pk[0] : pk[1];
      const unsigned pk23 = (q == 2) ? pk[2] : pk[3];
      const unsigned pkq  = (q < 2) ? pk01 : pk23;
      const float    iv01 = (q == 0) ? inv_x[0] : inv_x[1];
      const float    iv23 = (q == 2) ? inv_x[2] : inv_x[3];
      const float    invq = (q < 2) ? iv01 : iv23;
      const float val = (__uint_as_float(pkq & 0xFFFFFFC0u) - BIAS) * invq;
      stage[tid * NC_BLK + ci] = (_Float16)val;  // row w*64+q*16+wl == tid
      atomicAdd(&hist[ci * NLEAF + (int)(pkq & 63u)], 1u);
    }
  }

  __syncthreads();  // stage writes visible to all

  // Coalesced cos flush: rows [b_base,+512) x cols [c_base,+4).
  // Thread t owns row t: 8B stage read (contiguous), float4 global write.
  {
    half4h_t h = *(const half4h_t*)&stage[tid * NC_BLK];
    float4_t v;
    v.x = (float)h[0]; v.y = (float)h[1]; v.z = (float)h[2]; v.w = (float)h[3];
    *(float4_t*)&cos_out[(size_t)(b_base + tid) * NCATS + c_base] = v;
  }

  // Flush histogram (exact: integer-valued float atomics).
  if (tid < NC_BLK * NLEAF) {
    const unsigned v = hist[tid];
    if (v) atomicAdd(&counts_out[c_base * NLEAF + tid], (float)v);
  }
}

extern "C" void kernel_launch(void* const* d_in, const int* in_sizes, int n_in,
                              void* d_out, int out_size, void* d_ws, size_t ws_size,
                              hipStream_t stream) {
  const float* x   = (const float*)d_in[0];
  const float* e   = (const float*)d_in[1];
  const float* cin = (const float*)d_in[2];

  const int B = in_sizes[0] / D;                 // 65536
  float* cos_out = (float*)d_out;                // [B][64]
  float* counts_out = cos_out + (size_t)B * NCATS;

  char*  e16  = (char*)d_ws;                     // 1 MB fragment-major fp16 E
  char*  x16  = e16 + WS_E16_BYTES;              // 16 MB tiled fp16 x
  float* xinv = (float*)(x16 + WS_X16_BYTES);    // 256 KB f32 inv-norms

  const bool xp = (ws_size >= WS_NEEDED);
  const int prep_grid = xp ? (256 + B / 16) : 256;
  prep_kernel<<<prep_grid, 256, 0, stream>>>(e, x, e16, x16, xinv, cin, counts_out);

  const int main_grid = (B / BM) * (NCATS / NC_BLK);  // 2048
  if (xp)
    main_kernel<true><<<main_grid, 512, 0, stream>>>(x, e16, x16, xinv, cos_out, counts_out);
  else
    main_kernel<false><<<main_grid, 512, 0, stream>>>(x, e16, x16, xinv, cos_out, counts_out);
}

// Round 9
// 140.743 us; speedup vs baseline: 1.0151x; 1.0151x over previous
//
#include <hip/hip_runtime.h>
#include <stdint.h>
#include <stddef.h>

// Problem constants (fixed by the reference):
//   x:[B=65536][D=128] f32, E:[C=64][L=64][D=128] f32, counts:[64][64] f32
//   out0 = max_l cos(x_b, E_{c,l})  [B][C]
//   out1 = counts + bincount of argmax_l  [C][L]
#define D      128
#define NCATS  64
#define NLEAF  64
#define NC_BLK 4     // categories per block (c-split x16)
#define BM     512   // rows per block (8 waves x 64 batch cols)
#define BIAS   32.0f // dot ~ N(0,1) -> biased value positive -> uint order == float order

// Workspace layout: e16 [0,1MB) | x16 [1MB,17MB) | xinv [17MB,17.25MB)
#define WS_E16_BYTES   (1u << 20)
#define WS_X16_BYTES   (16u << 20)
#define WS_XINV_BYTES  (65536u * 4u)
#define WS_NEEDED      ((size_t)WS_E16_BYTES + WS_X16_BYTES + WS_XINV_BYTES)

typedef _Float16 half8_t  __attribute__((ext_vector_type(8)));
typedef _Float16 half4h_t __attribute__((ext_vector_type(4)));
typedef float    float4_t __attribute__((ext_vector_type(4)));

__device__ __forceinline__ void async_ld16(const void* g, void* l) {
  __builtin_amdgcn_global_load_lds((const __attribute__((address_space(1))) uint32_t*)g,
                                   (__attribute__((address_space(3))) uint32_t*)l,
                                   16, 0, 0);
}

__device__ __forceinline__ unsigned umax2(unsigned a, unsigned b) { return a > b ? a : b; }
// Nested so the compiler fuses to v_max3_u32.
__device__ __forceinline__ unsigned umax3(unsigned a, unsigned b, unsigned c) {
  return umax2(umax2(a, b), c);
}

// ---------------------------------------------------------------------------
// Prep (unchanged from R15):
//  blocks [0,256): E rows -> unit-normalized fp16 in FRAGMENT-MAJOR order:
//    per cat tile (16KB): frag (rt,s) at (rt*4+s)*1024, lane l's 16B at l*16
//    with l=(q,wl); main's LDS read is base+lane*16: linear, conflict-free
//    (R15 counter: 4.66M -> 463K). Seeds counts_out from cin (d_out poisoned).
//  blocks [256,4352) (XP mode): x rows -> RAW fp16 in 16-row tiles
//    (addr = g*4096 + chunk*256 + (row&15)*16) + inv_x[row] (f32).
// ---------------------------------------------------------------------------
__global__ __launch_bounds__(256) void prep_kernel(const float* __restrict__ e,
                                                   const float* __restrict__ xf,
                                                   char* __restrict__ e16,
                                                   char* __restrict__ x16,
                                                   float* __restrict__ xinv,
                                                   const float* __restrict__ cin,
                                                   float* __restrict__ counts_out) {
  const int t  = threadIdx.x;
  const int rl = t >> 4;  // row within this block's 16
  const int cc = t & 15;  // 16B chunk (8 halfs) within row

  if (blockIdx.x < 256) {
    const int row = blockIdx.x * 16 + rl;
    const float* src = e + (size_t)row * D + cc * 8;
    float4_t v0 = *(const float4_t*)src;
    float4_t v1 = *(const float4_t*)(src + 4);
    float ss = v0.x*v0.x + v0.y*v0.y + v0.z*v0.z + v0.w*v0.w +
               v1.x*v1.x + v1.y*v1.y + v1.z*v1.z + v1.w*v1.w;
    ss += __shfl_xor(ss, 1);
    ss += __shfl_xor(ss, 2);
    ss += __shfl_xor(ss, 4);
    ss += __shfl_xor(ss, 8);
    const float inv = 1.0f / fmaxf(sqrtf(ss), 1e-8f);
    half8_t h;
    h[0] = (_Float16)(v0.x * inv); h[1] = (_Float16)(v0.y * inv);
    h[2] = (_Float16)(v0.z * inv); h[3] = (_Float16)(v0.w * inv);
    h[4] = (_Float16)(v1.x * inv); h[5] = (_Float16)(v1.y * inv);
    h[6] = (_Float16)(v1.z * inv); h[7] = (_Float16)(v1.w * inv);
    // Fragment-major dest: cat | frag (rt,s) | lane (q,wl).
    const int cat = row >> 6;
    const int rt  = (row >> 4) & 3;
    const int wl  = row & 15;
    const int s   = cc >> 2;   // k-group
    const int q   = cc & 3;    // quad
    char* dst = e16 + (size_t)cat * 16384 + (rt * 4 + s) * 1024 + (q * 16 + wl) * 16;
    *(half8_t*)dst = h;
    if (blockIdx.x < (NCATS * NLEAF) / 256)
      counts_out[blockIdx.x * 256 + t] = cin[blockIdx.x * 256 + t];
  } else {
    const int g   = blockIdx.x - 256;     // 16-row group 0..4095
    const int row = g * 16 + rl;          // 0..65535
    const float* src = xf + (size_t)row * D + cc * 8;
    float4_t v0 = *(const float4_t*)src;
    float4_t v1 = *(const float4_t*)(src + 4);
    float ss = v0.x*v0.x + v0.y*v0.y + v0.z*v0.z + v0.w*v0.w +
               v1.x*v1.x + v1.y*v1.y + v1.z*v1.z + v1.w*v1.w;
    ss += __shfl_xor(ss, 1);
    ss += __shfl_xor(ss, 2);
    ss += __shfl_xor(ss, 4);
    ss += __shfl_xor(ss, 8);
    const float inv = 1.0f / fmaxf(sqrtf(ss), 1e-8f);
    half8_t h;  // RAW fp16 (main multiplies inv at epilogue, as before)
    h[0] = (_Float16)v0.x; h[1] = (_Float16)v0.y;
    h[2] = (_Float16)v0.z; h[3] = (_Float16)v0.w;
    h[4] = (_Float16)v1.x; h[5] = (_Float16)v1.y;
    h[6] = (_Float16)v1.z; h[7] = (_Float16)v1.w;
    *(half8_t*)(x16 + (size_t)g * 4096 + cc * 256 + rl * 16) = h;
    if (cc == 0) xinv[row] = inv;
  }
}

// ---------------------------------------------------------------------------
// Main (R16): R15 chassis (fragment-major conflict-free ebuf, fp16 x16/xinv,
// max3 pack, 64-lane writers) with OCCUPANCY DOUBLED:
//  * R15 counters: MfmaUtil 47 + VALUBusy 38 = 85, neither pipe >50%, at
//    4 waves/SIMD (LDS 70.6KB -> 2 blocks/CU). Dependency stalls uncovered.
//  * ebuf halved to 2 slots (32KB): ci 0,1 from slots 0,1; barrier; restage
//    tiles 2,3; barrier; ci 2,3. LDS 37.9KB -> 4 blocks/CU = 8 waves/SIMD.
//    Costs 2 barriers/block (~0.9us each at R9 pricing) vs 2x wave pool.
//  * c-split stays 16 -> no extra prologue redundancy.
//  * __launch_bounds__(512,4): cap 64 VGPR == R15's measured natural usage.
//    WATCH: any spill/scratch here kills the round (R11/R12 lesson).
// ---------------------------------------------------------------------------
template <bool XP>
__global__ __launch_bounds__(512, 4) void main_kernel(const float* __restrict__ x,
                                                      const char* __restrict__ e16,
                                                      const char* __restrict__ x16,
                                                      const float* __restrict__ xinv,
                                                      float* __restrict__ cos_out,
                                                      float* __restrict__ counts_out) {
  __shared__ __align__(16) char ebuf[2][16384];          // 32 KB, fragment-major
  __shared__ unsigned hist[NC_BLK * NLEAF];              // 1 KB
  __shared__ __align__(16) _Float16 stage[BM * NC_BLK];  // 4 KB, 8 B/row

  const int tid  = threadIdx.x;
  const int w    = tid >> 6;    // wave 0..7
  const int lane = tid & 63;
  const int q    = lane >> 4;   // MFMA quad
  const int wl   = lane & 15;

  // XCD-aware decode: bid = c_idx*128 + rb_local*8 + xcd.
  const int xcd    = blockIdx.x & 7;
  const int rb     = xcd * 16 + ((blockIdx.x >> 3) & 15);
  const int c_base = (blockIdx.x >> 7) * NC_BLK;
  const int b_base = rb * BM;

  // Stage tiles 0,1 into slots 0,1: wave w -> tile w>>2, quarter w&3
  // (4KB each: 4 x 1KB async DMA).
  {
    const char* g = e16 + (size_t)(c_base + (w >> 2)) * 16384 + (w & 3) * 4096 + lane * 16;
    char* l = &ebuf[w >> 2][(w & 3) * 4096 + lane * 16];
#pragma unroll
    for (int j = 0; j < 4; ++j) async_ld16(g + j * 1024, l + j * 1024);
  }

  if (tid < NC_BLK * NLEAF) hist[tid] = 0;

  // B = x fragments (verified lane layout: B[n=lane&15][k=quad*8+j]):
  // tile nt covers batch rows b_base + w*64 + nt*16 + [0,16).
  half8_t bfrag[4][4];
  float inv_x[4];
  if constexpr (XP) {
    const size_t gbase = ((size_t)b_base >> 4) + (size_t)w * 4;
#pragma unroll
    for (int nt = 0; nt < 4; ++nt) {
      const char* xr = x16 + (gbase + nt) * 4096 + q * 256 + wl * 16;
#pragma unroll
      for (int s = 0; s < 4; ++s)
        bfrag[nt][s] = *(const half8_t*)(xr + s * 1024);  // 1KB/instr coalesced
      inv_x[nt] = xinv[b_base + w * 64 + nt * 16 + wl];
    }
  } else {
#pragma unroll
    for (int nt = 0; nt < 4; ++nt) {
      const int row = b_base + w * 64 + nt * 16 + wl;
      const float* xr = x + (size_t)row * D;
      float ss = 0.f;
#pragma unroll
      for (int s = 0; s < 4; ++s) {
        const float* p = xr + s * 32 + q * 8;
        float4_t v0 = *(const float4_t*)p;
        float4_t v1 = *(const float4_t*)(p + 4);
        half8_t h;
        h[0] = (_Float16)v0.x; h[1] = (_Float16)v0.y;
        h[2] = (_Float16)v0.z; h[3] = (_Float16)v0.w;
        h[4] = (_Float16)v1.x; h[5] = (_Float16)v1.y;
        h[6] = (_Float16)v1.z; h[7] = (_Float16)v1.w;
        bfrag[nt][s] = h;
        ss += v0.x*v0.x + v0.y*v0.y + v0.z*v0.z + v0.w*v0.w +
              v1.x*v1.x + v1.y*v1.y + v1.z*v1.z + v1.w*v1.w;
      }
      ss += __shfl_xor(ss, 16);
      ss += __shfl_xor(ss, 32);
      inv_x[nt] = 1.0f / fmaxf(sqrtf(ss), 1e-8f);
    }
  }

  const int lofs = lane * 16;               // fragment-major lane offset
  const unsigned idq = (unsigned)(q << 2);  // leaf-index bits {2,3} (lane const)
  const float4_t bias4 = {BIAS, BIAS, BIAS, BIAS};

  __syncthreads();  // drains tile 0,1 DMA (vmcnt0) + hist init

#pragma unroll
  for (int half = 0; half < 2; ++half) {
    if (half == 1) {
      __syncthreads();  // all waves done reading slots 0,1
      // Restage tiles 2,3 into slots 0,1 (same wave split).
      const char* g = e16 + (size_t)(c_base + 2 + (w >> 2)) * 16384 + (w & 3) * 4096 + lane * 16;
      char* l = &ebuf[w >> 2][(w & 3) * 4096 + lane * 16];
#pragma unroll
      for (int j = 0; j < 4; ++j) async_ld16(g + j * 1024, l + j * 1024);
      __syncthreads();  // per-wave vmcnt0 drain + barrier -> all DMA visible
    }
#pragma unroll
    for (int sub = 0; sub < 2; ++sub) {
      const int ci = half * 2 + sub;
      const char* cur = &ebuf[sub][lofs];

      // rt-outer: acc[4] (one per batch tile nt) live at a time. C/D layout:
      // col = lane&15 = batch-within-tile, row = q*4+reg = leaf-within-tile.
      // Keys carry leaf idx bits {0,1}=reg, {4,5}=rt; bits {2,3}(=q) OR'd
      // once before the cross-lane combine.
      unsigned pk[4];
      __builtin_amdgcn_s_setprio(1);
#pragma unroll
      for (int rt = 0; rt < 4; ++rt) {
        float4_t acc[4];
#pragma unroll
        for (int s = 0; s < 4; ++s) {
          half8_t ef = *(const half8_t*)(cur + (rt * 4 + s) * 1024);  // linear, conflict-free
#pragma unroll
          for (int nt = 0; nt < 4; ++nt)
            acc[nt] = __builtin_amdgcn_mfma_f32_16x16x32_f16(
                ef, bfrag[nt][s], (s == 0) ? bias4 : acc[nt], 0, 0, 0);
        }
        // Pack via max3 tree (keys are positive floats: dot+BIAS ~ 32+-5).
#pragma unroll
        for (int nt = 0; nt < 4; ++nt) {
          const unsigned k0 = (__float_as_uint(acc[nt][0]) & 0xFFFFFFC0u) | (unsigned)(rt * 16 + 0);
          const unsigned k1 = (__float_as_uint(acc[nt][1]) & 0xFFFFFFC0u) | (unsigned)(rt * 16 + 1);
          const unsigned k2 = (__float_as_uint(acc[nt][2]) & 0xFFFFFFC0u) | (unsigned)(rt * 16 + 2);
          const unsigned k3 = (__float_as_uint(acc[nt][3]) & 0xFFFFFFC0u) | (unsigned)(rt * 16 + 3);
          const unsigned m  = umax3(k0, k1, k2);
          pk[nt] = (rt == 0) ? umax2(m, k3) : umax3(m, k3, pk[nt]);
        }
      }
      __builtin_amdgcn_s_setprio(0);

      // Cross-lane: combine the 4 quads of this batch col. EXPLICIT TEMPS,
      // unconditional shuffles (R3 lesson).
#pragma unroll
      for (int nt = 0; nt < 4; ++nt) {
        unsigned v = pk[nt] | idq;
        unsigned t = (unsigned)__shfl_xor((int)v, 16);
        v = (v > t) ? v : t;
        t = (unsigned)__shfl_xor((int)v, 32);
        v = (v > t) ? v : t;
        pk[nt] = v;  // quad-uniform for this wl
      }

      // Writers spread over all 64 lanes: lane (q,wl) handles nt=q. pk[q] is
      // quad-uniform; inv_x[nt] is wl-determined -> every lane holds the
      // right inv. Constant-index selects only (no runtime indexing).
      {
        const unsigned pk01 = (q == 0) ? pk[0] : pk[1];
        const unsigned pk23 = (q == 2) ? pk[2] : pk[3];
        const unsigned pkq  = (q < 2) ? pk01 : pk23;
        const float    iv01 = (q == 0) ? inv_x[0] : inv_x[1];
        const float    iv23 = (q == 2) ? inv_x[2] : inv_x[3];
        const float    invq = (q < 2) ? iv01 : iv23;
        const float val = (__uint_as_float(pkq & 0xFFFFFFC0u) - BIAS) * invq;
        stage[tid * NC_BLK + ci] = (_Float16)val;  // row w*64+q*16+wl == tid
        atomicAdd(&hist[ci * NLEAF + (int)(pkq & 63u)], 1u);
      }
    }
  }

  __syncthreads();  // stage writes visible to all

  // Coalesced cos flush: rows [b_base,+512) x cols [c_base,+4).
  // Thread t owns row t: 8B stage read (contiguous), float4 global write.
  {
    half4h_t h = *(const half4h_t*)&stage[tid * NC_BLK];
    float4_t v;
    v.x = (float)h[0]; v.y = (float)h[1]; v.z = (float)h[2]; v.w = (float)h[3];
    *(float4_t*)&cos_out[(size_t)(b_base + tid) * NCATS + c_base] = v;
  }

  // Flush histogram (exact: integer-valued float atomics).
  if (tid < NC_BLK * NLEAF) {
    const unsigned v = hist[tid];
    if (v) atomicAdd(&counts_out[c_base * NLEAF + tid], (float)v);
  }
}

extern "C" void kernel_launch(void* const* d_in, const int* in_sizes, int n_in,
                              void* d_out, int out_size, void* d_ws, size_t ws_size,
                              hipStream_t stream) {
  const float* x   = (const float*)d_in[0];
  const float* e   = (const float*)d_in[1];
  const float* cin = (const float*)d_in[2];

  const int B = in_sizes[0] / D;                 // 65536
  float* cos_out = (float*)d_out;                // [B][64]
  float* counts_out = cos_out + (size_t)B * NCATS;

  char*  e16  = (char*)d_ws;                     // 1 MB fragment-major fp16 E
  char*  x16  = e16 + WS_E16_BYTES;              // 16 MB tiled fp16 x
  float* xinv = (float*)(x16 + WS_X16_BYTES);    // 256 KB f32 inv-norms

  const bool xp = (ws_size >= WS_NEEDED);
  const int prep_grid = xp ? (256 + B / 16) : 256;
  prep_kernel<<<prep_grid, 256, 0, stream>>>(e, x, e16, x16, xinv, cin, counts_out);

  const int main_grid = (B / BM) * (NCATS / NC_BLK);  // 2048
  if (xp)
    main_kernel<true><<<main_grid, 512, 0, stream>>>(x, e16, x16, xinv, cos_out, counts_out);
  else
    main_kernel<false><<<main_grid, 512, 0, stream>>>(x, e16, x16, xinv, cos_out, counts_out);
}